// Round 1
// 1558.088 us; speedup vs baseline: 1.2616x; 1.2616x over previous
//
#include <hip/hip_runtime.h>

typedef unsigned short u16;
typedef unsigned int u32;
typedef __attribute__((ext_vector_type(8))) __bf16 bf16x8;
typedef __attribute__((ext_vector_type(4))) float f32x4;

#define D_ 1024
#define H_ 4096
#define E_ 8
#define NT_ 4096          // B*T tokens
#define RCAP_ 8320        // 8192 assignment rows + 128 pad (GEMM tiles may over-read)

// ---------- helpers ----------
__device__ __forceinline__ u16 f2b(float f) {   // fp32 -> bf16 bits, RNE
  u32 u = __float_as_uint(f);
  u += 0x7fffu + ((u >> 16) & 1u);
  return (u16)(u >> 16);
}

__device__ __forceinline__ void glds16(const u16* g, u16* l) {
  // async global->LDS, 16B per lane; LDS dest = wave-uniform base + lane*16
  __builtin_amdgcn_global_load_lds((const __attribute__((address_space(1))) void*)g,
                                   (__attribute__((address_space(3))) void*)l, 16, 0, 0);
}

// ---------- small kernels ----------
__global__ void init_ints(int* p, int n) {
  int i = threadIdx.x;
  if (i < n) p[i] = 0;
}

__global__ void cvt_f32_bf16(const float* __restrict__ in, u16* __restrict__ out) {
  int i = blockIdx.x * blockDim.x + threadIdx.x;   // one per 4 elements
  float4 v = ((const float4*)in)[i];
  u32 lo = (u32)f2b(v.x) | ((u32)f2b(v.y) << 16);
  u32 hi = (u32)f2b(v.z) | ((u32)f2b(v.w) << 16);
  ((uint2*)out)[i] = make_uint2(lo, hi);
}

// in: [R][C] f32  ->  out: [C][R] bf16   (batched over blockIdx.z)
__global__ void transpose_cvt(const float* __restrict__ in, u16* __restrict__ out, int R, int C) {
  __shared__ float t[64][65];
  size_t base = (size_t)blockIdx.z * R * C;
  in += base; out += base;
  int c0 = blockIdx.x * 64, r0 = blockIdx.y * 64;
  int tx = threadIdx.x, ty = threadIdx.y;   // 64, 4
#pragma unroll
  for (int i = 0; i < 16; ++i)
    t[ty + 4 * i][tx] = in[(size_t)(r0 + ty + 4 * i) * C + c0 + tx];
  __syncthreads();
#pragma unroll
  for (int i = 0; i < 16; ++i)
    out[(size_t)(c0 + ty + 4 * i) * R + r0 + tx] = f2b(t[tx][ty + 4 * i]);
}

// fp32 noisy top-2 router: one wave per token
__global__ void router_k(const float* __restrict__ x, const float* __restrict__ noise,
                         const float* __restrict__ Wr, const float* __restrict__ br,
                         const float* __restrict__ Wn, const float* __restrict__ bn,
                         int* __restrict__ counts, int* __restrict__ tok_e,
                         float* __restrict__ tok_g) {
  const int t = blockIdx.x;
  const int lane = threadIdx.x;
  float xv[16];
#pragma unroll
  for (int i = 0; i < 16; ++i) xv[i] = x[(size_t)t * D_ + lane + 64 * i];
  float nz[E_];
#pragma unroll
  for (int e = 0; e < E_; ++e) {
    float ar = 0.f, an = 0.f;
#pragma unroll
    for (int i = 0; i < 16; ++i) {
      int d = lane + 64 * i;
      ar += xv[i] * Wr[d * E_ + e];
      an += xv[i] * Wn[d * E_ + e];
    }
#pragma unroll
    for (int o = 32; o > 0; o >>= 1) {
      ar += __shfl_down(ar, o, 64);
      an += __shfl_down(an, o, 64);
    }
    if (lane == 0) {
      float lg = ar + br[e], nl = an + bn[e];
      float sp = (nl > 20.f) ? nl : log1pf(expf(nl));     // softplus
      nz[e] = lg + noise[(size_t)t * E_ + e] * sp;
    }
  }
  if (lane == 0) {
    int i0 = 0;
#pragma unroll
    for (int e = 1; e < E_; ++e) if (nz[e] > nz[i0]) i0 = e;
    int i1 = (i0 == 0) ? 1 : 0;
#pragma unroll
    for (int e = 0; e < E_; ++e) if (e != i0 && nz[e] > nz[i1]) i1 = e;
    float a = nz[i0], b = nz[i1];
    float m = fmaxf(a, b);
    float ea = expf(a - m), eb = expf(b - m);
    float inv = 1.f / (ea + eb);
    tok_e[2 * t] = i0; tok_e[2 * t + 1] = i1;
    tok_g[2 * t] = ea * inv; tok_g[2 * t + 1] = eb * inv;
    atomicAdd(&counts[i0], 1);
    atomicAdd(&counts[i1], 1);
  }
}

__global__ void scan_k(const int* __restrict__ counts, int* __restrict__ offsets) {
  if (threadIdx.x == 0) {
    int acc = 0;
    for (int e = 0; e < E_; ++e) { offsets[e] = acc; acc += counts[e]; }
    offsets[E_] = acc;
  }
}

// gather token rows into per-expert contiguous blocks (bf16), record row->token/gate
__global__ void gather_k(const u16* __restrict__ xb, const int* __restrict__ tok_e,
                         const float* __restrict__ tok_g, const int* __restrict__ offsets,
                         int* __restrict__ cursors, u16* __restrict__ Xall,
                         int* __restrict__ row_token, float* __restrict__ row_gate) {
  const int t = blockIdx.x;
  __shared__ int rws[2];
  if (threadIdx.x < 2) {
    int e = tok_e[2 * t + threadIdx.x];
    int r = offsets[e] + atomicAdd(&cursors[e], 1);
    row_token[r] = t;
    row_gate[r] = tok_g[2 * t + threadIdx.x];
    rws[threadIdx.x] = r;
  }
  __syncthreads();
  const uint4* src = (const uint4*)(xb + (size_t)t * D_);
  uint4 v0 = src[threadIdx.x], v1 = src[threadIdx.x + 64];
  uint4* d0 = (uint4*)(Xall + (size_t)rws[0] * D_);
  uint4* d1 = (uint4*)(Xall + (size_t)rws[1] * D_);
  d0[threadIdx.x] = v0; d0[threadIdx.x + 64] = v1;
  d1[threadIdx.x] = v0; d1[threadIdx.x + 64] = v1;
}

// ---------- GEMM1: act[m][n] = silu(A@Wg) * (A@Wu), bf16 out ----------
// A: [rows][K] bf16 (K-contig), Wg/Wu: [E][H][K] bf16 (B^T layout), tiles 128x128x32
// 2-phase double-buffered K-loop (T3-minimum): issue next-tile global_load_lds BEFORE
// computing current tile; one vmcnt(0)+barrier per step (latency hides under MFMA).
__global__ __launch_bounds__(256, 2)
void gemm1_swiglu(const u16* __restrict__ Abase, const u16* __restrict__ Wg,
                  const u16* __restrict__ Wu, u16* __restrict__ act,
                  const int* __restrict__ neArr, const int* __restrict__ offArr,
                  int fixedM, int K) {
  int bx, by, bz;
  if (neArr) {
    // routed path: expert -> XCD swizzle. HW round-robins linear block id over 8 XCDs,
    // so lid&7 pins each expert to one XCD: its 2MB A-slab stays L2-resident across
    // all 32 n-panels (m fast within XCD shares the B-panel; n slow streams weights once).
    const int lid = blockIdx.x + 32 * (blockIdx.y + 32 * blockIdx.z);
    bz = lid & 7;
    const int rest = lid >> 3;
    bx = rest & 31;
    by = rest >> 5;
  } else { bx = blockIdx.x; by = blockIdx.y; bz = blockIdx.z; }
  const int e = bz;
  const int ne = neArr ? neArr[e] : fixedM;
  const int m0 = bx * 128;
  if (m0 >= ne) return;
  const int off = offArr ? offArr[e] : 0;
  const int n0 = by * 128;
  const u16* A  = Abase + (size_t)(off + m0) * K;
  const u16* Bg = Wg + (size_t)e * H_ * K + (size_t)n0 * K;
  const u16* Bu = Wu + (size_t)e * H_ * K + (size_t)n0 * K;

  __shared__ __align__(16) u16 As[2][128 * 32], Bgs[2][128 * 32], Bus[2][128 * 32];

  const int tid = threadIdx.x;
  const int lane = tid & 63, wv = tid >> 6;
  const int wm = (wv >> 1) * 64, wn = (wv & 1) * 64;
  const int lm = lane & 15, lq = lane >> 4;
  const int sr = wv * 32 + (lane >> 2);
  const int sk = (lane & 3) * 8;

  f32x4 accg[4][4] = {};
  f32x4 accu[4][4] = {};

  const int NKT = K >> 5;
  // prologue: stage tile 0 into buffer 0
#pragma unroll
  for (int c = 0; c < 2; ++c) {
    const size_t go = (size_t)(sr + c * 16) * K + sk;
    glds16(A + go,  &As [0][(wv * 32 + c * 16) * 32]);
    glds16(Bg + go, &Bgs[0][(wv * 32 + c * 16) * 32]);
    glds16(Bu + go, &Bus[0][(wv * 32 + c * 16) * 32]);
  }
  asm volatile("s_waitcnt vmcnt(0)" ::: "memory");
  __builtin_amdgcn_s_barrier();

  int cur = 0;
  for (int t = 0; t < NKT; ++t) {
    if (t + 1 < NKT) {   // issue next tile's loads; they fly during this tile's compute
      const int kt = (t + 1) << 5;
#pragma unroll
      for (int c = 0; c < 2; ++c) {
        const size_t go = (size_t)(sr + c * 16) * K + kt + sk;
        glds16(A + go,  &As [cur ^ 1][(wv * 32 + c * 16) * 32]);
        glds16(Bg + go, &Bgs[cur ^ 1][(wv * 32 + c * 16) * 32]);
        glds16(Bu + go, &Bus[cur ^ 1][(wv * 32 + c * 16) * 32]);
      }
    }
    bf16x8 af[4], bg[4], bu[4];
#pragma unroll
    for (int i = 0; i < 4; ++i) {
      af[i] = *(const bf16x8*)(As [cur] + (wm + i * 16 + lm) * 32 + lq * 8);
      bg[i] = *(const bf16x8*)(Bgs[cur] + (wn + i * 16 + lm) * 32 + lq * 8);
      bu[i] = *(const bf16x8*)(Bus[cur] + (wn + i * 16 + lm) * 32 + lq * 8);
    }
#pragma unroll
    for (int i = 0; i < 4; ++i)
#pragma unroll
      for (int j = 0; j < 4; ++j) {
        accg[i][j] = __builtin_amdgcn_mfma_f32_16x16x32_bf16(af[i], bg[j], accg[i][j], 0, 0, 0);
        accu[i][j] = __builtin_amdgcn_mfma_f32_16x16x32_bf16(af[i], bu[j], accu[i][j], 0, 0, 0);
      }
    asm volatile("s_waitcnt vmcnt(0)" ::: "memory");
    __builtin_amdgcn_s_barrier();
    cur ^= 1;
  }
  // C/D layout: col = lane&15, row = (lane>>4)*4 + reg  (m89-verified)
#pragma unroll
  for (int i = 0; i < 4; ++i)
#pragma unroll
    for (int r = 0; r < 4; ++r) {
      const int m = m0 + wm + i * 16 + lq * 4 + r;
      if (m < ne) {
        u16* dst = act + (size_t)(off + m) * H_ + n0 + wn + lm;
#pragma unroll
        for (int j = 0; j < 4; ++j) {
          float g = accg[i][j][r], u = accu[i][j][r];
          float s = g / (1.f + __expf(-g)) * u;
          dst[j * 16] = f2b(s);
        }
      }
    }
}

// ---------- GEMM2: out = A @ Wd ; plain store (shared) or gated atomic scatter (routed) ----------
__global__ __launch_bounds__(256, 2)
void gemm2_k(const u16* __restrict__ Abase, const u16* __restrict__ Wd,
             float* __restrict__ out,
             const int* __restrict__ neArr, const int* __restrict__ offArr,
             const int* __restrict__ row_token, const float* __restrict__ row_gate,
             int fixedM, int K) {
  const int e = blockIdx.z;
  const int ne = neArr ? neArr[e] : fixedM;
  const int m0 = blockIdx.x * 128;
  if (m0 >= ne) return;
  const int off = offArr ? offArr[e] : 0;
  const int n0 = blockIdx.y * 128;
  const u16* A = Abase + (size_t)(off + m0) * K;
  const u16* B = Wd + (size_t)e * D_ * K + (size_t)n0 * K;

  __shared__ __align__(16) u16 As[2][128 * 32], Bs[2][128 * 32];

  const int tid = threadIdx.x;
  const int lane = tid & 63, wv = tid >> 6;
  const int wm = (wv >> 1) * 64, wn = (wv & 1) * 64;
  const int lm = lane & 15, lq = lane >> 4;
  const int sr = wv * 32 + (lane >> 2);
  const int sk = (lane & 3) * 8;

  f32x4 acc[4][4] = {};

  const int NKT = K >> 5;
  // prologue: stage tile 0 into buffer 0
#pragma unroll
  for (int c = 0; c < 2; ++c) {
    const size_t go = (size_t)(sr + c * 16) * K + sk;
    glds16(A + go, &As[0][(wv * 32 + c * 16) * 32]);
    glds16(B + go, &Bs[0][(wv * 32 + c * 16) * 32]);
  }
  asm volatile("s_waitcnt vmcnt(0)" ::: "memory");
  __builtin_amdgcn_s_barrier();

  int cur = 0;
  for (int t = 0; t < NKT; ++t) {
    if (t + 1 < NKT) {
      const int kt = (t + 1) << 5;
#pragma unroll
      for (int c = 0; c < 2; ++c) {
        const size_t go = (size_t)(sr + c * 16) * K + kt + sk;
        glds16(A + go, &As[cur ^ 1][(wv * 32 + c * 16) * 32]);
        glds16(B + go, &Bs[cur ^ 1][(wv * 32 + c * 16) * 32]);
      }
    }
    bf16x8 af[4], bfb[4];
#pragma unroll
    for (int i = 0; i < 4; ++i) {
      af[i]  = *(const bf16x8*)(As[cur] + (wm + i * 16 + lm) * 32 + lq * 8);
      bfb[i] = *(const bf16x8*)(Bs[cur] + (wn + i * 16 + lm) * 32 + lq * 8);
    }
#pragma unroll
    for (int i = 0; i < 4; ++i)
#pragma unroll
      for (int j = 0; j < 4; ++j)
        acc[i][j] = __builtin_amdgcn_mfma_f32_16x16x32_bf16(af[i], bfb[j], acc[i][j], 0, 0, 0);
    asm volatile("s_waitcnt vmcnt(0)" ::: "memory");
    __builtin_amdgcn_s_barrier();
    cur ^= 1;
  }

#pragma unroll
  for (int i = 0; i < 4; ++i)
#pragma unroll
    for (int r = 0; r < 4; ++r) {
      const int m = m0 + wm + i * 16 + lq * 4 + r;
      if (m < ne) {
        const int n = n0 + wn + lm;
        if (row_token) {
          const int t = row_token[off + m];
          const float gt = row_gate[off + m];
#pragma unroll
          for (int j = 0; j < 4; ++j)
            atomicAdd(out + (size_t)t * D_ + n + j * 16, gt * acc[i][j][r]);
        } else {
#pragma unroll
          for (int j = 0; j < 4; ++j)
            out[(size_t)m * D_ + n + j * 16] = acc[i][j][r];
        }
      }
    }
}

// ---------- host ----------
extern "C" void kernel_launch(void* const* d_in, const int* in_sizes, int n_in,
                              void* d_out, int out_size, void* d_ws, size_t ws_size,
                              hipStream_t stream) {
  const float* x     = (const float*)d_in[0];
  const float* noise = (const float*)d_in[1];
  const float* Wr    = (const float*)d_in[2];
  const float* br    = (const float*)d_in[3];
  const float* Wn    = (const float*)d_in[4];
  const float* bn    = (const float*)d_in[5];
  const float* Wg    = (const float*)d_in[6];
  const float* Wu    = (const float*)d_in[7];
  const float* Wd    = (const float*)d_in[8];
  const float* Sg    = (const float*)d_in[9];
  const float* Su    = (const float*)d_in[10];
  const float* Sd    = (const float*)d_in[11];
  float* out = (float*)d_out;

  char* base = (char*)d_ws;
  size_t off = 0;
  auto take = [&](size_t bytes) -> void* {
    void* r = base + off;
    off = (off + bytes + 255) & ~(size_t)255;
    return r;
  };
  u16* WgT = (u16*)take((size_t)E_ * H_ * D_ * 2);   // [E][H][D] bf16
  u16* WuT = (u16*)take((size_t)E_ * H_ * D_ * 2);
  u16* WdT = (u16*)take((size_t)E_ * D_ * H_ * 2);   // [E][D][H] bf16
  u16* SgT = (u16*)take((size_t)H_ * D_ * 2);
  u16* SuT = (u16*)take((size_t)H_ * D_ * 2);
  u16* SdT = (u16*)take((size_t)D_ * H_ * 2);
  u16* xb  = (u16*)take((size_t)NT_ * D_ * 2);
  u16* Xall = (u16*)take((size_t)RCAP_ * D_ * 2);
  u16* act  = (u16*)take((size_t)RCAP_ * H_ * 2);    // shared phase uses rows [0,4096)
  int*   row_token = (int*)take(RCAP_ * 4);
  float* row_gate  = (float*)take(RCAP_ * 4);
  int*   tok_e = (int*)take(NT_ * 2 * 4);
  float* tok_g = (float*)take(NT_ * 2 * 4);
  int* ints = (int*)take(32 * 4);                    // counts[8] cursors[8] offsets[9]
  int* counts = ints, *cursors = ints + 8, *offsets = ints + 16;
  if (off > ws_size) return;   // ws too small: clean no-op fail (absmax would be 1.99)

  hipLaunchKernelGGL(init_ints, dim3(1), dim3(64), 0, stream, ints, 32);
  hipLaunchKernelGGL(cvt_f32_bf16, dim3(NT_ * D_ / 4 / 256), dim3(256), 0, stream, x, xb);
  dim3 tb(64, 4);
  hipLaunchKernelGGL(transpose_cvt, dim3(H_ / 64, D_ / 64, E_), tb, 0, stream, Wg, WgT, D_, H_);
  hipLaunchKernelGGL(transpose_cvt, dim3(H_ / 64, D_ / 64, E_), tb, 0, stream, Wu, WuT, D_, H_);
  hipLaunchKernelGGL(transpose_cvt, dim3(D_ / 64, H_ / 64, E_), tb, 0, stream, Wd, WdT, H_, D_);
  hipLaunchKernelGGL(transpose_cvt, dim3(H_ / 64, D_ / 64, 1), tb, 0, stream, Sg, SgT, D_, H_);
  hipLaunchKernelGGL(transpose_cvt, dim3(H_ / 64, D_ / 64, 1), tb, 0, stream, Su, SuT, D_, H_);
  hipLaunchKernelGGL(transpose_cvt, dim3(D_ / 64, H_ / 64, 1), tb, 0, stream, Sd, SdT, H_, D_);

  hipLaunchKernelGGL(router_k, dim3(NT_), dim3(64), 0, stream,
                     x, noise, Wr, br, Wn, bn, counts, tok_e, tok_g);
  hipLaunchKernelGGL(scan_k, dim3(1), dim3(64), 0, stream, counts, offsets);
  hipLaunchKernelGGL(gather_k, dim3(NT_), dim3(64), 0, stream,
                     xb, tok_e, tok_g, offsets, cursors, Xall, row_token, row_gate);

  // shared expert (all tokens): act = swiglu(x@Sg, x@Su); out = act@Sd (plain store, inits d_out)
  hipLaunchKernelGGL(gemm1_swiglu, dim3(32, 32, 1), dim3(256), 0, stream,
                     xb, SgT, SuT, act, (const int*)nullptr, (const int*)nullptr, NT_, D_);
  hipLaunchKernelGGL(gemm2_k, dim3(32, 8, 1), dim3(256), 0, stream,
                     act, SdT, out, (const int*)nullptr, (const int*)nullptr,
                     (const int*)nullptr, (const float*)nullptr, NT_, H_);
  // routed experts (gathered rows): act = swiglu(Xe@Wg_e, Xe@Wu_e); out += gate * act@Wd_e
  hipLaunchKernelGGL(gemm1_swiglu, dim3(32, 32, E_), dim3(256), 0, stream,
                     Xall, WgT, WuT, act, counts, offsets, 0, D_);
  hipLaunchKernelGGL(gemm2_k, dim3(32, 8, E_), dim3(256), 0, stream,
                     act, WdT, out, counts, offsets, row_token, row_gate, 0, H_);
}